// Round 1
// 1163.808 us; speedup vs baseline: 1.3358x; 1.3358x over previous
//
#include <hip/hip_runtime.h>
#include <cmath>

// (B,C,H,W)=(8,256,128,128), hidden=512, CHUNK=64
#define BATCH 8
#define CDIM 256
#define HWDIM 16384
#define MDIM 131072
#define HIDDEN 512

typedef unsigned short u16;
typedef unsigned int u32;
typedef short bf16x8 __attribute__((ext_vector_type(8)));
typedef float floatx4 __attribute__((ext_vector_type(4)));
typedef __attribute__((address_space(3))) unsigned int as3_u32;
typedef __attribute__((address_space(1))) const unsigned int as1_u32;

__device__ __forceinline__ float bfu(u16 u) {
    union { u32 i; float f; } p; p.i = ((u32)u) << 16; return p.f;
}
__device__ __forceinline__ float blo(u32 u) {
    union { u32 i; float f; } p; p.i = u << 16; return p.f;
}
__device__ __forceinline__ float bhi(u32 u) {
    union { u32 i; float f; } p; p.i = u & 0xFFFF0000u; return p.f;
}
__device__ __forceinline__ u16 fbf(float f) {   // fp32 -> bf16 RNE
    union { float f; u32 i; } p; p.f = f;
    u32 r = p.i + 0x7FFFu + ((p.i >> 16) & 1u);
    return (u16)(r >> 16);
}
__device__ __forceinline__ float gelu_f(float v) {
    return 0.5f * v * (1.0f + erff(v * 0.70710678118654752f));
}
__device__ __forceinline__ void gl_lds16(const u16* g, u16* l) {
    __builtin_amdgcn_global_load_lds((as1_u32*)(const void*)g,
                                     (as3_u32*)(void*)l, 16, 0, 0);
}

// ---------------------------------------------------------------------------
// LayerNorm over channels: x (B,C,HW) fp32 NCHW -> out (B*HW, C) bf16 rows
__global__ __launch_bounds__(256) void ln_k(const float* __restrict__ x,
                                            const float* __restrict__ sc,
                                            const float* __restrict__ bi,
                                            u16* __restrict__ out)
{
    const int idx = blockIdx.x * 256 + threadIdx.x;
    const int b = idx >> 14;
    const int n = idx & 16383;
    const float* xp = x + ((size_t)b << 22) + n;
    float s = 0.f, s2 = 0.f;
    for (int c = 0; c < CDIM; ++c) {
        const float v = xp[(size_t)c << 14];
        s += v; s2 += v * v;
    }
    const float mu = s * (1.f / CDIM);
    const float var = s2 * (1.f / CDIM) - mu * mu;
    const float r = rsqrtf(var + 1e-5f);
    u16* op = out + ((size_t)idx << 8);
    for (int c = 0; c < CDIM; c += 2) {
        const float v0 = (xp[(size_t)c << 14] - mu) * r * sc[c] + bi[c];
        const float v1 = (xp[(size_t)(c + 1) << 14] - mu) * r * sc[c + 1] + bi[c + 1];
        const u32 o = ((u32)fbf(v1) << 16) | fbf(v0);
        *(u32*)(op + c) = o;
    }
}

// ---------------------------------------------------------------------------
// MFMA GEMM: C(M x NN) = A(M x K, bf16 row-major) * Wt(NN x K, fp32)^T
// Tile 128(M) x 64(N) x 64(K). 4 waves, each 64x32 via 4x2 mfma_16x16x32_bf16.
template<int K, int NN, int EPI>
__global__ __launch_bounds__(256) void mgemm(const u16* __restrict__ A,
                                             const float* __restrict__ Wt,
                                             const float* __restrict__ bias,
                                             const float* __restrict__ res,
                                             float* __restrict__ outF,
                                             u16* __restrict__ outB)
{
    __shared__ u16 smem[12288];          // As 128x64 (16KB) + Bs 64x64 (8KB)
    u16* As = smem;
    u16* Bs = smem + 8192;
    const int t = threadIdx.x;
    const int l = t & 63, w = t >> 6;
    const int m0 = blockIdx.x * 128;
    const int j0 = blockIdx.y * 64;
    const int wm = (w >> 1) * 64, wn = (w & 1) * 32;
    floatx4 acc[4][2] = {};

    for (int k0 = 0; k0 < K; k0 += 64) {
        #pragma unroll
        for (int it = 0; it < 4; ++it) {
            const int q = it * 256 + t;
            const int r = q >> 3, pq = q & 7;
            const int kq = pq ^ (r & 7);
            const u16* g = A + (size_t)(m0 + r) * K + k0 + kq * 8;
            gl_lds16(g, As + (size_t)(it * 256 + w * 64) * 8);
        }
        #pragma unroll
        for (int it = 0; it < 2; ++it) {
            const int q = it * 256 + t;
            const int r = q >> 3, pq = q & 7;
            const int kq = pq ^ (r & 7);
            const float* g = Wt + (size_t)(j0 + r) * K + k0 + kq * 8;
            const float4 w0 = *(const float4*)g;
            const float4 w1 = *(const float4*)(g + 4);
            uint4 pk;
            pk.x = ((u32)fbf(w0.y) << 16) | fbf(w0.x);
            pk.y = ((u32)fbf(w0.w) << 16) | fbf(w0.z);
            pk.z = ((u32)fbf(w1.y) << 16) | fbf(w1.x);
            pk.w = ((u32)fbf(w1.w) << 16) | fbf(w1.z);
            *(uint4*)(Bs + q * 8) = pk;
        }
        __syncthreads();
        #pragma unroll
        for (int ks = 0; ks < 2; ++ks) {
            bf16x8 af[4], bfr[2];
            const int kq = ks * 4 + (l >> 4);
            #pragma unroll
            for (int mi = 0; mi < 4; ++mi) {
                const int r = wm + mi * 16 + (l & 15);
                const int pq = kq ^ (r & 7);
                af[mi] = *(const bf16x8*)(As + r * 64 + pq * 8);
            }
            #pragma unroll
            for (int ni = 0; ni < 2; ++ni) {
                const int r = wn + ni * 16 + (l & 15);
                const int pq = kq ^ (r & 7);
                bfr[ni] = *(const bf16x8*)(Bs + r * 64 + pq * 8);
            }
            #pragma unroll
            for (int mi = 0; mi < 4; ++mi)
                #pragma unroll
                for (int ni = 0; ni < 2; ++ni)
                    acc[mi][ni] = __builtin_amdgcn_mfma_f32_16x16x32_bf16(
                        af[mi], bfr[ni], acc[mi][ni], 0, 0, 0);
        }
        __syncthreads();
    }

    float bv[2];
    #pragma unroll
    for (int ni = 0; ni < 2; ++ni)
        bv[ni] = bias[j0 + wn + ni * 16 + (l & 15)];

    if constexpr (EPI == 0 || EPI == 2) {
        u16* Cs = smem;
        #pragma unroll
        for (int mi = 0; mi < 4; ++mi) {
            #pragma unroll
            for (int ni = 0; ni < 2; ++ni) {
                const int col = wn + ni * 16 + (l & 15);
                #pragma unroll
                for (int r = 0; r < 4; ++r) {
                    const int row = wm + mi * 16 + (l >> 4) * 4 + r;
                    float v = acc[mi][ni][r] + bv[ni];
                    if constexpr (EPI == 2) v = gelu_f(v);
                    const int pc = ((col >> 3) ^ (row & 7)) * 8 + (col & 7);
                    Cs[row * 64 + pc] = fbf(v);
                }
            }
        }
        __syncthreads();
        #pragma unroll
        for (int it = 0; it < 4; ++it) {
            const int q = it * 256 + t;
            const int row = q >> 3, pcq = q & 7;
            const int cq = pcq ^ (row & 7);
            *(uint4*)(outB + (size_t)(m0 + row) * NN + j0 + cq * 8) =
                *(const uint4*)(Cs + q * 8);
        }
    } else {
        #pragma unroll
        for (int mi = 0; mi < 4; ++mi) {
            const int m = m0 + wm + mi * 16 + (l >> 4) * 4;
            const int b = m >> 14, n = m & 16383;
            #pragma unroll
            for (int ni = 0; ni < 2; ++ni) {
                const int j = j0 + wn + ni * 16 + (l & 15);
                const size_t idx = ((size_t)(b * NN + j) << 14) + n;
                const float4 rv = *(const float4*)(res + idx);
                float4 o;
                o.x = acc[mi][ni][0] + bv[ni] + rv.x;
                o.y = acc[mi][ni][1] + bv[ni] + rv.y;
                o.z = acc[mi][ni][2] + bv[ni] + rv.z;
                o.w = acc[mi][ni][3] + bv[ni] + rv.w;
                *(float4*)(outF + idx) = o;
            }
        }
    }
}

// ---------------------------------------------------------------------------
// MFMA chunked attention. One block (4 waves) per 64-token chunk.
// Wave w owns query strip [w*16, w*16+16).
//   S = Q·K^T via mfma(A=Q rows, B=K rows)  -> D[col=key, row=query]
//   softmax: wave-parallel shfl_xor over the 16-lane column groups
//   O = P·V via mfma(A=P rows, B=V^T rows)  -> D[col=chan, row=query]
// K staged row-major via global_load_lds with pre-swizzled source granules
// (granule ^= row&7); V^T staged by register transpose with the same XOR;
// P (bf16) reuses the first 8KB of the K buffer after a barrier.
__global__ __launch_bounds__(256) void attn_m(const u16* __restrict__ qkv,
                                              u16* __restrict__ ao)
{
    __shared__ u16 Ks[64 * 256];   // 32KB K chunk (granule-swizzled); P reuses [0,4096)
    __shared__ u16 Vt[256 * 64];   // 32KB V^T chunk (granule-swizzled)
    const int t = threadIdx.x;
    const int l = t & 63, w = t >> 6;
    const int lr = l & 15, lh = l >> 4;
    const size_t base = (size_t)blockIdx.x * 64;
    const u16* qk = qkv + base * 768;

    // ---- stage K: 2048 16B granules, dest linear, source pre-swizzled ----
    #pragma unroll
    for (int it = 0; it < 8; ++it) {
        const int p = it * 256 + t;
        const int row = p >> 5;                    // token 0..63
        const int gq = (p & 31) ^ (row & 7);       // swizzled source granule
        gl_lds16(qk + row * 768 + 256 + gq * 8,
                 Ks + (size_t)(it * 256 + w * 64) * 8);
    }
    // ---- stage V^T: register transpose, u32 (2 tokens) per LDS write ----
    #pragma unroll
    for (int it = 0; it < 4; ++it) {
        const int p = it * 256 + t;                // 1024 (token-pair, chan8) groups
        const int tok2 = (p & 31) * 2;
        const int c8 = (p >> 5) * 8;
        const uint4 v0 = *(const uint4*)(qk + (size_t)tok2 * 768 + 512 + c8);
        const uint4 v1 = *(const uint4*)(qk + (size_t)(tok2 + 1) * 768 + 512 + c8);
        const u32 a0[4] = { v0.x, v0.y, v0.z, v0.w };
        const u32 a1[4] = { v1.x, v1.y, v1.z, v1.w };
        #pragma unroll
        for (int i = 0; i < 8; ++i) {
            const int c = c8 + i;
            const u32 lo = (a0[i >> 1] >> ((i & 1) * 16)) & 0xFFFFu;
            const u32 hi = (a1[i >> 1] >> ((i & 1) * 16)) & 0xFFFFu;
            *(u32*)&Vt[c * 64 + (tok2 ^ ((c & 7) << 3))] = lo | (hi << 16);
        }
    }
    __syncthreads();

    // ---- QK^T: 16 queries per wave, Q straight from global (64B/token) ----
    floatx4 sa[4] = {};
    const u16* qg = qk + (size_t)(w * 16 + lr) * 768;
    #pragma unroll
    for (int s = 0; s < 8; ++s) {
        const bf16x8 aq = *(const bf16x8*)(qg + s * 32 + lh * 8);
        #pragma unroll
        for (int tk = 0; tk < 4; ++tk) {
            const int row = tk * 16 + lr;
            const int g = (s * 4 + lh) ^ (row & 7);
            const bf16x8 bk = *(const bf16x8*)(Ks + row * 256 + g * 8);
            sa[tk] = __builtin_amdgcn_mfma_f32_16x16x32_bf16(aq, bk, sa[tk], 0, 0, 0);
        }
    }
    __syncthreads();   // all waves done reading K before P overwrites Ks[0..4095]

    // ---- softmax: lane holds queries 4*lh+r at key col lr (+16*tk) ----
    float inv[4];
    #pragma unroll
    for (int r = 0; r < 4; ++r) {
        const float v0 = sa[0][r] * 0.0625f, v1 = sa[1][r] * 0.0625f;
        const float v2 = sa[2][r] * 0.0625f, v3 = sa[3][r] * 0.0625f;
        float m = fmaxf(fmaxf(v0, v1), fmaxf(v2, v3));
        m = fmaxf(m, __shfl_xor(m, 1));
        m = fmaxf(m, __shfl_xor(m, 2));
        m = fmaxf(m, __shfl_xor(m, 4));
        m = fmaxf(m, __shfl_xor(m, 8));
        const float e0 = expf(v0 - m), e1 = expf(v1 - m);
        const float e2 = expf(v2 - m), e3 = expf(v3 - m);
        float ssum = (e0 + e1) + (e2 + e3);
        ssum += __shfl_xor(ssum, 1);
        ssum += __shfl_xor(ssum, 2);
        ssum += __shfl_xor(ssum, 4);
        ssum += __shfl_xor(ssum, 8);
        inv[r] = 1.f / ssum;
        const int qrow = w * 16 + lh * 4 + r;
        const int swz = (qrow & 7) << 3;
        Ks[qrow * 64 + ((0 * 16 + lr) ^ swz)] = fbf(e0);
        Ks[qrow * 64 + ((1 * 16 + lr) ^ swz)] = fbf(e1);
        Ks[qrow * 64 + ((2 * 16 + lr) ^ swz)] = fbf(e2);
        Ks[qrow * 64 + ((3 * 16 + lr) ^ swz)] = fbf(e3);
    }
    __syncthreads();

    // ---- PV: O[q][c] = sum_k P[q][k] V[k][c], normalize in epilogue ----
    floatx4 oa[16] = {};
    #pragma unroll
    for (int ks = 0; ks < 2; ++ks) {
        const int qrow = w * 16 + lr;
        const int gp = (ks * 4 + lh) ^ (qrow & 7);
        const bf16x8 ap = *(const bf16x8*)(Ks + qrow * 64 + gp * 8);
        #pragma unroll
        for (int tc = 0; tc < 16; ++tc) {
            const int c = tc * 16 + lr;
            const int gv = (ks * 4 + lh) ^ (c & 7);
            const bf16x8 bv = *(const bf16x8*)(Vt + c * 64 + gv * 8);
            oa[tc] = __builtin_amdgcn_mfma_f32_16x16x32_bf16(ap, bv, oa[tc], 0, 0, 0);
        }
    }
    u16* aop = ao + (base + w * 16 + lh * 4) * 256;
    #pragma unroll
    for (int r = 0; r < 4; ++r) {
        #pragma unroll
        for (int tc = 0; tc < 16; ++tc)
            aop[(size_t)r * 256 + tc * 16 + lr] = fbf(oa[tc][r] * inv[r]);
    }
}

// ---------------------------------------------------------------------------
// Depthwise 3x3 + bias + GELU, channel-last bf16 (M,512), 8 channels/thread.
__global__ __launch_bounds__(256) void dwconv_v8(const u16* __restrict__ h1,
                                                 const float* __restrict__ w,
                                                 const float* __restrict__ b2,
                                                 u16* __restrict__ h2)
{
    const int g = blockIdx.x * 256 + threadIdx.x;   // over M*64 groups
    const int cb = (g & 63) * 8;                    // base channel of group
    const int n = g >> 6;
    const int x = n & 127, y = (n >> 7) & 127, b = n >> 14;
    const u16* in = h1 + (((size_t)b << 14) << 9);  // batch base (n*512)

    float wr[72];
    #pragma unroll
    for (int i = 0; i < 18; ++i)
        *(float4*)&wr[i * 4] = *(const float4*)(w + cb * 9 + i * 4);

    float acc[8];
    {
        const float4 bl = *(const float4*)(b2 + cb);
        const float4 bh = *(const float4*)(b2 + cb + 4);
        acc[0] = bl.x; acc[1] = bl.y; acc[2] = bl.z; acc[3] = bl.w;
        acc[4] = bh.x; acc[5] = bh.y; acc[6] = bh.z; acc[7] = bh.w;
    }

    #pragma unroll
    for (int dy = -1; dy <= 1; ++dy) {
        const int yy = y + dy;
        if (yy < 0 || yy > 127) continue;           // wave-uniform
        #pragma unroll
        for (int dx = -1; dx <= 1; ++dx) {
            const int xx = x + dx;
            if (xx < 0 || xx > 127) continue;       // wave-uniform
            const int tap = (dy + 1) * 3 + (dx + 1);
            const uint4 v = *(const uint4*)(in + (size_t)(((yy << 7) + xx) << 9) + cb);
            const u32 p[4] = { v.x, v.y, v.z, v.w };
            #pragma unroll
            for (int q = 0; q < 4; ++q) {
                acc[2 * q + 0] = fmaf(wr[(2 * q + 0) * 9 + tap], blo(p[q]), acc[2 * q + 0]);
                acc[2 * q + 1] = fmaf(wr[(2 * q + 1) * 9 + tap], bhi(p[q]), acc[2 * q + 1]);
            }
        }
    }

    uint4 o;
    u32* op = (u32*)&o;
    #pragma unroll
    for (int q = 0; q < 4; ++q) {
        const float g0 = gelu_f(acc[2 * q + 0]);
        const float g1 = gelu_f(acc[2 * q + 1]);
        op[q] = ((u32)fbf(g1) << 16) | fbf(g0);
    }
    *(uint4*)(h2 + (size_t)n * 512 + cb) = o;
}

// ---------------------------------------------------------------------------
extern "C" void kernel_launch(void* const* d_in, const int* in_sizes, int n_in,
                              void* d_out, int out_size, void* d_ws, size_t ws_size,
                              hipStream_t stream)
{
    (void)in_sizes; (void)n_in; (void)out_size; (void)ws_size;
    const float* x     = (const float*)d_in[0];
    const float* ln1s  = (const float*)d_in[1];
    const float* ln1b  = (const float*)d_in[2];
    const float* qkvw  = (const float*)d_in[3];
    const float* qkvb  = (const float*)d_in[4];
    const float* projw = (const float*)d_in[5];
    const float* projb = (const float*)d_in[6];
    const float* ln2s  = (const float*)d_in[7];
    const float* ln2b  = (const float*)d_in[8];
    const float* w1    = (const float*)d_in[9];
    const float* b1    = (const float*)d_in[10];
    const float* w2    = (const float*)d_in[11];
    const float* b2    = (const float*)d_in[12];
    const float* w3    = (const float*)d_in[13];
    const float* b3    = (const float*)d_in[14];
    float* out = (float*)d_out;
    char* ws = (char*)d_ws;

    u16* XLN = (u16*)(ws);
    u16* QKV = (u16*)(ws + (size_t)67108864);
    u16* AO  = (u16*)(ws + (size_t)268435456);
    u16* YLN = XLN;
    u16* H1  = (u16*)(ws + (size_t)67108864);
    u16* H2  = (u16*)(ws + (size_t)201326592);

    ln_k<<<dim3(MDIM / 256), dim3(256), 0, stream>>>(x, ln1s, ln1b, XLN);
    mgemm<256, 768, 0><<<dim3(1024, 12), dim3(256), 0, stream>>>(XLN, qkvw, qkvb, nullptr, nullptr, QKV);
    attn_m<<<dim3(MDIM / 64), dim3(256), 0, stream>>>(QKV, AO);
    mgemm<256, 256, 1><<<dim3(1024, 4), dim3(256), 0, stream>>>(AO, projw, projb, x, out, nullptr);
    ln_k<<<dim3(MDIM / 256), dim3(256), 0, stream>>>(out, ln2s, ln2b, YLN);
    mgemm<256, 512, 2><<<dim3(1024, 8), dim3(256), 0, stream>>>(YLN, w1, b1, nullptr, nullptr, H1);
    dwconv_v8<<<dim3((MDIM * 64) / 256), dim3(256), 0, stream>>>(H1, w2, b2, H2);
    mgemm<512, 256, 3><<<dim3(1024, 4), dim3(256), 0, stream>>>(H2, w3, b3, out, out, nullptr);
}